// Round 2
// baseline (521.412 us; speedup 1.0000x reference)
//
#include <hip/hip_runtime.h>

// Problem: B=4, N=8192, CIN=256, H=8, D=64, INNER=512, COUT=256. All fp32 I/O.
// out[b] = u_x[b] @ Mb[b] + bo, where
//   Mb[c,o] = (1/N) sum_{h,d,e} Wq[h*64+d,c] * dots[b,h,d,e] * Wo[o,h*64+e]
//   dots[b,h] = knorm^T vnorm  (InstanceNorm over D per (b,h,n))
// ws (floats): dots[131072] | S[524288] | Mb[262144]  = 3.67 MB

#define B_    4
#define N_    8192
#define CIN_  256
#define H_    8
#define D_    64
#define INNER_ 512
#define COUT_ 256
#define EPS_  1e-5f

// ---------------------------------------------------------------------------
// Kernel 1: grid (16 chunks, 8 h, 4 b), 256 thr. Block owns 512 rows, loops
// 8 sub-tiles of 64 rows: GEMM 64x128 (K|V for head h), InstanceNorm rows,
// accumulate 64x64 dots in regs across sub-tiles, one atomicAdd pass at end.
// LDS: 4352 + 8448 + 33792 = 46.6 KB.
// ---------------------------------------------------------------------------
__global__ __launch_bounds__(256) void kv_dots_kernel(
    const float* __restrict__ u_x, const float* __restrict__ Wk,
    const float* __restrict__ Wv, float* __restrict__ dots)
{
  __shared__ __align__(16) float As[16][68];    // A slab: 16 cols x 64 rows (transposed)
  __shared__ __align__(16) float Bs[16][132];   // B slab: 16 cols x 128 wrows (transposed)
  __shared__ __align__(16) float KV[64][132];   // K|V tile: 64 rows x 128

  const int t = threadIdx.x;
  const int chunk = blockIdx.x, h = blockIdx.y, b = blockIdx.z;
  const int tr = t >> 4, tc = t & 15;        // 16x16 thread grid
  const int ar = t >> 2, ac = (t & 3) * 4;   // A staging: 64 rows x 16 cols
  const int br = t >> 1, bc = (t & 1) * 8;   // B staging: 128 wrows x 16 cols

  const float* wrow = (br < 64) ? Wk + (size_t)(h * 64 + br) * CIN_
                                : Wv + (size_t)(h * 64 + br - 64) * CIN_;

  float dl[4][4];
#pragma unroll
  for (int i = 0; i < 4; i++)
#pragma unroll
    for (int j = 0; j < 4; j++) dl[i][j] = 0.f;

  for (int st = 0; st < 8; st++) {
    const int r0 = chunk * 512 + st * 64;
    float acc[4][8];
#pragma unroll
    for (int i = 0; i < 4; i++)
#pragma unroll
      for (int j = 0; j < 8; j++) acc[i][j] = 0.f;

    const float* arow = u_x + ((size_t)(b * N_) + r0 + ar) * CIN_ + ac;

    for (int c0 = 0; c0 < CIN_; c0 += 16) {
      const float4 a4  = *(const float4*)(arow + c0);
      const float4 b40 = *(const float4*)(wrow + c0 + bc);
      const float4 b41 = *(const float4*)(wrow + c0 + bc + 4);
      As[ac + 0][ar] = a4.x; As[ac + 1][ar] = a4.y;
      As[ac + 2][ar] = a4.z; As[ac + 3][ar] = a4.w;
      Bs[bc + 0][br] = b40.x; Bs[bc + 1][br] = b40.y;
      Bs[bc + 2][br] = b40.z; Bs[bc + 3][br] = b40.w;
      Bs[bc + 4][br] = b41.x; Bs[bc + 5][br] = b41.y;
      Bs[bc + 6][br] = b41.z; Bs[bc + 7][br] = b41.w;
      __syncthreads();
#pragma unroll
      for (int cc = 0; cc < 16; cc++) {
        const float4 a  = *(const float4*)&As[cc][tr * 4];
        const float4 p0 = *(const float4*)&Bs[cc][tc * 8];
        const float4 p1 = *(const float4*)&Bs[cc][tc * 8 + 4];
        const float av[4] = {a.x, a.y, a.z, a.w};
        const float bv[8] = {p0.x, p0.y, p0.z, p0.w, p1.x, p1.y, p1.z, p1.w};
#pragma unroll
        for (int i = 0; i < 4; i++)
#pragma unroll
          for (int j = 0; j < 8; j++) acc[i][j] = fmaf(av[i], bv[j], acc[i][j]);
      }
      __syncthreads();
    }

    // spill tile
#pragma unroll
    for (int i = 0; i < 4; i++)
#pragma unroll
      for (int j = 0; j < 8; j++) KV[tr * 4 + i][tc * 8 + j] = acc[i][j];
    __syncthreads();

    // InstanceNorm: 128 threads, one per (row, 64-wide half); biased var.
    if (t < 128) {
      float* row = &KV[t >> 1][(t & 1) * 64];
      float s = 0.f;
#pragma unroll 8
      for (int c = 0; c < 64; c++) s += row[c];
      const float mean = s * (1.f / 64.f);
      float v = 0.f;
#pragma unroll 8
      for (int c = 0; c < 64; c++) { const float d = row[c] - mean; v = fmaf(d, d, v); }
      const float inv = rsqrtf(v * (1.f / 64.f) + EPS_);
#pragma unroll 8
      for (int c = 0; c < 64; c++) row[c] = (row[c] - mean) * inv;
    }
    __syncthreads();

    // dots += k^T v over this sub-tile; thread owns 4x4 of 64x64
    for (int n = 0; n < 64; n++) {
      const float4 kk = *(const float4*)&KV[n][tr * 4];
      const float4 vv = *(const float4*)&KV[n][64 + tc * 4];
      const float ka[4] = {kk.x, kk.y, kk.z, kk.w};
      const float va[4] = {vv.x, vv.y, vv.z, vv.w};
#pragma unroll
      for (int i = 0; i < 4; i++)
#pragma unroll
        for (int j = 0; j < 4; j++) dl[i][j] = fmaf(ka[i], va[j], dl[i][j]);
    }
    __syncthreads();
  }

  float* dg = dots + ((size_t)(b * H_ + h)) * 4096;
#pragma unroll
  for (int i = 0; i < 4; i++)
#pragma unroll
    for (int j = 0; j < 4; j++)
      atomicAdd(&dg[(tr * 4 + i) * 64 + tc * 4 + j], dl[i][j]);
}

// ---------------------------------------------------------------------------
// Kernel 2a: S[b][hd][o] = sum_e dots[b,h,d,e] * Wo[o, h*64+e]
// ---------------------------------------------------------------------------
__global__ __launch_bounds__(256) void s_kernel(
    const float* __restrict__ dots, const float* __restrict__ Wo,
    float* __restrict__ S)
{
  const int blk = blockIdx.x;  // b*512 + hd
  const int b = blk >> 9, hd = blk & 511, h = hd >> 6;
  __shared__ float drow[64];
  const int t = threadIdx.x;
  if (t < 64) drow[t] = dots[((size_t)(b * H_ + h)) * 4096 + (hd & 63) * 64 + t];
  __syncthreads();
  const float* wp = Wo + (size_t)t * INNER_ + h * 64;
  float acc = 0.f;
#pragma unroll
  for (int e = 0; e < 64; e += 4) {
    const float4 w = *(const float4*)(wp + e);
    acc = fmaf(drow[e + 0], w.x, acc);
    acc = fmaf(drow[e + 1], w.y, acc);
    acc = fmaf(drow[e + 2], w.z, acc);
    acc = fmaf(drow[e + 3], w.w, acc);
  }
  S[((size_t)(b * INNER_) + hd) * COUT_ + t] = acc;
}

// ---------------------------------------------------------------------------
// Kernel 2b: Mb[b][c][o] = (1/N) sum_hd Wq[hd][c] * S[b][hd][o]
// grid (16 c-tiles, 4 b), 256 thr; thread owns o=t for 16 c values.
// ---------------------------------------------------------------------------
__global__ __launch_bounds__(256) void mb_kernel(
    const float* __restrict__ Wq, const float* __restrict__ S,
    float* __restrict__ Mb)
{
  __shared__ __align__(16) float wql[INNER_][16];
  const int c0 = blockIdx.x * 16, b = blockIdx.y;
  const int t = threadIdx.x;
#pragma unroll
  for (int i = 0; i < 32; i++) {
    const int idx = i * 256 + t;  // 0..8191
    wql[idx >> 4][idx & 15] = Wq[(size_t)(idx >> 4) * CIN_ + c0 + (idx & 15)];
  }
  __syncthreads();
  float acc[16];
#pragma unroll
  for (int cp = 0; cp < 16; cp++) acc[cp] = 0.f;
  const float* sp = S + (size_t)b * INNER_ * COUT_ + t;
  for (int hd = 0; hd < INNER_; hd++) {
    const float sv = sp[(size_t)hd * COUT_];
#pragma unroll
    for (int g = 0; g < 4; g++) {
      const float4 w = *(const float4*)&wql[hd][g * 4];
      acc[g * 4 + 0] = fmaf(w.x, sv, acc[g * 4 + 0]);
      acc[g * 4 + 1] = fmaf(w.y, sv, acc[g * 4 + 1]);
      acc[g * 4 + 2] = fmaf(w.z, sv, acc[g * 4 + 2]);
      acc[g * 4 + 3] = fmaf(w.w, sv, acc[g * 4 + 3]);
    }
  }
#pragma unroll
  for (int cp = 0; cp < 16; cp++)
    Mb[((size_t)(b * CIN_) + c0 + cp) * COUT_ + t] = acc[cp] * (1.0f / N_);
}

// ---------------------------------------------------------------------------
// Kernel 3: out[b,n,o] = sum_c u_x[b,n,c] * Mb[b][c][o] + bo[o]
// 128x128 tiles, 8x8 per thread.
// ---------------------------------------------------------------------------
__global__ __launch_bounds__(256) void out_kernel(
    const float* __restrict__ u_x, const float* __restrict__ Mb,
    const float* __restrict__ bo, float* __restrict__ out)
{
  __shared__ __align__(16) float As[16][132];
  __shared__ __align__(16) float Bs[16][132];
  const int t = threadIdx.x;
  const int r0 = blockIdx.x * 128, o0 = blockIdx.y * 128, b = blockIdx.z;
  const int tr = t >> 4, tc = t & 15;
  const int lr = t >> 1, lcoff = (t & 1) * 8;
  const int mcc = t >> 4, mooff = (t & 15) * 8;

  float acc[8][8];
#pragma unroll
  for (int i = 0; i < 8; i++)
#pragma unroll
    for (int j = 0; j < 8; j++) acc[i][j] = 0.f;

  const float* arow = u_x + ((size_t)(b * N_) + r0 + lr) * CIN_ + lcoff;

  for (int c0 = 0; c0 < CIN_; c0 += 16) {
    const float4 a0 = *(const float4*)(arow + c0);
    const float4 a1 = *(const float4*)(arow + c0 + 4);
    const float* mp = Mb + ((size_t)(b * CIN_) + c0 + mcc) * COUT_ + o0 + mooff;
    const float4 m0 = *(const float4*)mp;
    const float4 m1 = *(const float4*)(mp + 4);
    As[lcoff + 0][lr] = a0.x; As[lcoff + 1][lr] = a0.y;
    As[lcoff + 2][lr] = a0.z; As[lcoff + 3][lr] = a0.w;
    As[lcoff + 4][lr] = a1.x; As[lcoff + 5][lr] = a1.y;
    As[lcoff + 6][lr] = a1.z; As[lcoff + 7][lr] = a1.w;
    *(float4*)&Bs[mcc][mooff]     = m0;
    *(float4*)&Bs[mcc][mooff + 4] = m1;
    __syncthreads();
#pragma unroll
    for (int cc = 0; cc < 16; cc++) {
      const float4 x0 = *(const float4*)&As[cc][tr * 8];
      const float4 x1 = *(const float4*)&As[cc][tr * 8 + 4];
      const float4 y0 = *(const float4*)&Bs[cc][tc * 8];
      const float4 y1 = *(const float4*)&Bs[cc][tc * 8 + 4];
      const float av[8] = {x0.x, x0.y, x0.z, x0.w, x1.x, x1.y, x1.z, x1.w};
      const float bv[8] = {y0.x, y0.y, y0.z, y0.w, y1.x, y1.y, y1.z, y1.w};
#pragma unroll
      for (int i = 0; i < 8; i++)
#pragma unroll
        for (int j = 0; j < 8; j++) acc[i][j] = fmaf(av[i], bv[j], acc[i][j]);
    }
    __syncthreads();
  }

  float bov[8];
#pragma unroll
  for (int j = 0; j < 8; j++) bov[j] = bo[o0 + tc * 8 + j];
#pragma unroll
  for (int i = 0; i < 8; i++) {
    float* op = out + ((size_t)(b * N_) + r0 + tr * 8 + i) * COUT_ + o0 + tc * 8;
    float4 r0v, r1v;
    r0v.x = acc[i][0] + bov[0]; r0v.y = acc[i][1] + bov[1];
    r0v.z = acc[i][2] + bov[2]; r0v.w = acc[i][3] + bov[3];
    r1v.x = acc[i][4] + bov[4]; r1v.y = acc[i][5] + bov[5];
    r1v.z = acc[i][6] + bov[6]; r1v.w = acc[i][7] + bov[7];
    *(float4*)op = r0v;
    *(float4*)(op + 4) = r1v;
  }
}

extern "C" void kernel_launch(void* const* d_in, const int* in_sizes, int n_in,
                              void* d_out, int out_size, void* d_ws, size_t ws_size,
                              hipStream_t stream) {
  const float* u_x = (const float*)d_in[0];
  // d_in[1] = pos_x (unused by the reference computation)
  const float* Wq = (const float*)d_in[2];
  const float* Wk = (const float*)d_in[3];
  const float* Wv = (const float*)d_in[4];
  const float* Wo = (const float*)d_in[5];
  const float* bo = (const float*)d_in[6];
  float* out = (float*)d_out;

  float* dots = (float*)d_ws;       // 131072 floats
  float* S    = dots + 131072;      // 524288 floats
  float* Mb   = S + 524288;         // 262144 floats

  hipMemsetAsync(dots, 0, 131072 * sizeof(float), stream);
  kv_dots_kernel<<<dim3(16, 8, 4), 256, 0, stream>>>(u_x, Wk, Wv, dots);
  s_kernel<<<2048, 256, 0, stream>>>(dots, Wo, S);
  mb_kernel<<<dim3(16, 4), 256, 0, stream>>>(Wq, S, Mb);
  out_kernel<<<dim3(64, 2, 4), 256, 0, stream>>>(u_x, Mb, bo, out);
}

// Round 3
// 316.682 us; speedup vs baseline: 1.6465x; 1.6465x over previous
//
#include <hip/hip_runtime.h>

// B=4, N=8192, CIN=256, H=8, D=64, INNER=512, COUT=256. fp32 I/O.
// out[b] = u_x[b] @ Mb[b]^T' + bo  via collapsed per-batch 256x256 matrix.
// GEMMs run as split-bf16 MFMA (x = hi + lo, 3 mfma terms, rel err ~2^-16).
// ws (floats): dots[131072] | S[524288] | MbtH[131072] | MbtL[131072] = 3.5 MB

#define B_    4
#define N_    8192
#define CIN_  256
#define H_    8
#define D_    64
#define INNER_ 512
#define COUT_ 256
#define EPS_  1e-5f

typedef unsigned short ushort_t;
typedef unsigned int   uint_t;
typedef __attribute__((ext_vector_type(8))) short short8;
typedef __attribute__((ext_vector_type(4))) float f32x4;

__device__ __forceinline__ void split_bf16(float x, ushort_t& hi, ushort_t& lo) {
  const uint_t u = __float_as_uint(x);
  const uint_t hr = (u + 0x8000u) & 0xffff0000u;   // round-half-up to bf16
  hi = (ushort_t)(hr >> 16);
  const float l = x - __uint_as_float(hr);          // exact residual
  lo = (ushort_t)((__float_as_uint(l) + 0x8000u) >> 16);
}

__device__ __forceinline__ void cvt8(float4 x, float4 y, uint4& uh, uint4& ul) {
  const float v[8] = {x.x, x.y, x.z, x.w, y.x, y.y, y.z, y.w};
  ushort_t h[8], l[8];
#pragma unroll
  for (int j = 0; j < 8; j++) split_bf16(v[j], h[j], l[j]);
  uh = make_uint4(h[0] | ((uint_t)h[1] << 16), h[2] | ((uint_t)h[3] << 16),
                  h[4] | ((uint_t)h[5] << 16), h[6] | ((uint_t)h[7] << 16));
  ul = make_uint4(l[0] | ((uint_t)l[1] << 16), l[2] | ((uint_t)l[3] << 16),
                  l[4] | ((uint_t)l[5] << 16), l[6] | ((uint_t)l[7] << 16));
}

#define MFMA(A, Bv, C) __builtin_amdgcn_mfma_f32_16x16x32_bf16((A), (Bv), (C), 0, 0, 0)

// ---------------------------------------------------------------------------
// Kernel 1: per (chunk of 128 rows, h, b): KV = u_x_tile @ [Wk_h;Wv_h]^T via
// split-bf16 MFMA (128x128 tile, 4 waves of 64x64), then per-64-row halves:
// spill fp32 -> LDS, InstanceNorm rows, VALU-accumulate 64x64 dots, atomicAdd.
// LDS: staging 4x(4x130x8 ushort)=33280 B, reused as KV spill 64x132 f32=33792 B.
// ---------------------------------------------------------------------------
__global__ __launch_bounds__(256, 2) void kv_dots_kernel(
    const float* __restrict__ u_x, const float* __restrict__ Wk,
    const float* __restrict__ Wv, float* __restrict__ dots)
{
  __shared__ __align__(16) char smem[33792];
  ushort_t (*Ah)[130][8] = (ushort_t(*)[130][8])(smem);
  ushort_t (*Al)[130][8] = (ushort_t(*)[130][8])(smem + 8320);
  ushort_t (*Bh)[130][8] = (ushort_t(*)[130][8])(smem + 16640);
  ushort_t (*Bl)[130][8] = (ushort_t(*)[130][8])(smem + 24960);
  float (*KVl)[132] = (float(*)[132])smem;

  const int t = threadIdx.x;
  const int chunk = blockIdx.x, h = blockIdx.y, b = blockIdx.z;
  const int r0 = chunk * 128;
  const int lane = t & 63, wave = t >> 6;
  const int q = lane >> 4, r = lane & 15;
  const int m0 = (wave >> 1) * 64, n0 = (wave & 1) * 64;
  const int srow = t >> 1, scs = (t & 1) * 16, q0 = (t & 1) * 2;

  const float* ag = u_x + ((size_t)(b * N_) + r0 + srow) * CIN_ + scs;
  const float* bg = (srow < 64) ? Wk + (size_t)(h * 64 + srow) * CIN_ + scs
                                : Wv + (size_t)(h * 64 + srow - 64) * CIN_ + scs;

  f32x4 acc[4][4];
#pragma unroll
  for (int i = 0; i < 4; i++)
#pragma unroll
    for (int j = 0; j < 4; j++) acc[i][j] = (f32x4)0.f;

  for (int kc = 0; kc < 8; kc++) {
    {  // stage 32 c-columns of A (128 rows) and B (128 w-rows), split hi/lo
      const float4* ap = (const float4*)(ag + kc * 32);
      const float4* bp = (const float4*)(bg + kc * 32);
      uint4 uh, ul;
      cvt8(ap[0], ap[1], uh, ul);
      *(uint4*)&Ah[q0][srow][0] = uh;  *(uint4*)&Al[q0][srow][0] = ul;
      cvt8(ap[2], ap[3], uh, ul);
      *(uint4*)&Ah[q0 + 1][srow][0] = uh;  *(uint4*)&Al[q0 + 1][srow][0] = ul;
      cvt8(bp[0], bp[1], uh, ul);
      *(uint4*)&Bh[q0][srow][0] = uh;  *(uint4*)&Bl[q0][srow][0] = ul;
      cvt8(bp[2], bp[3], uh, ul);
      *(uint4*)&Bh[q0 + 1][srow][0] = uh;  *(uint4*)&Bl[q0 + 1][srow][0] = ul;
    }
    __syncthreads();
    short8 ahf[4], alf[4];
#pragma unroll
    for (int mi = 0; mi < 4; mi++) {
      ahf[mi] = *(const short8*)&Ah[q][m0 + 16 * mi + r][0];
      alf[mi] = *(const short8*)&Al[q][m0 + 16 * mi + r][0];
    }
#pragma unroll
    for (int nj = 0; nj < 4; nj++) {
      const short8 bhv = *(const short8*)&Bh[q][n0 + 16 * nj + r][0];
      const short8 blv = *(const short8*)&Bl[q][n0 + 16 * nj + r][0];
#pragma unroll
      for (int mi = 0; mi < 4; mi++) {
        acc[mi][nj] = MFMA(ahf[mi], bhv, acc[mi][nj]);
        acc[mi][nj] = MFMA(alf[mi], bhv, acc[mi][nj]);
        acc[mi][nj] = MFMA(ahf[mi], blv, acc[mi][nj]);
      }
    }
    __syncthreads();
  }

  // Two 64-row passes: spill -> norm -> dots accumulate
  float dl[4][4];
#pragma unroll
  for (int i = 0; i < 4; i++)
#pragma unroll
    for (int j = 0; j < 4; j++) dl[i][j] = 0.f;
  const int tr = t >> 4, tc = t & 15;

  for (int p = 0; p < 2; p++) {
    if ((wave >> 1) == p) {
#pragma unroll
      for (int mi = 0; mi < 4; mi++)
#pragma unroll
        for (int nj = 0; nj < 4; nj++) {
          const f32x4 v = acc[mi][nj];
#pragma unroll
          for (int reg = 0; reg < 4; reg++)
            KVl[16 * mi + q * 4 + reg][n0 + 16 * nj + r] = v[reg];
        }
    }
    __syncthreads();
    if (t < 128) {  // InstanceNorm: one thread per (row, 64-wide half)
      float* row = &KVl[t >> 1][(t & 1) * 64];
      float s = 0.f;
#pragma unroll
      for (int c = 0; c < 64; c += 4) {
        const float4 x = *(const float4*)(row + c);
        s += x.x + x.y + x.z + x.w;
      }
      const float mean = s * (1.f / 64.f);
      float vv = 0.f;
#pragma unroll
      for (int c = 0; c < 64; c += 4) {
        const float4 x = *(const float4*)(row + c);
        const float d0 = x.x - mean, d1 = x.y - mean, d2 = x.z - mean, d3 = x.w - mean;
        vv = fmaf(d0, d0, vv); vv = fmaf(d1, d1, vv);
        vv = fmaf(d2, d2, vv); vv = fmaf(d3, d3, vv);
      }
      const float inv = rsqrtf(vv * (1.f / 64.f) + EPS_);
#pragma unroll
      for (int c = 0; c < 64; c += 4) {
        float4 x = *(const float4*)(row + c);
        x.x = (x.x - mean) * inv; x.y = (x.y - mean) * inv;
        x.z = (x.z - mean) * inv; x.w = (x.w - mean) * inv;
        *(float4*)(row + c) = x;
      }
    }
    __syncthreads();
    for (int n = 0; n < 64; n++) {
      const float4 kk = *(const float4*)&KVl[n][tr * 4];
      const float4 vx = *(const float4*)&KVl[n][64 + tc * 4];
      const float ka[4] = {kk.x, kk.y, kk.z, kk.w};
      const float va[4] = {vx.x, vx.y, vx.z, vx.w};
#pragma unroll
      for (int i = 0; i < 4; i++)
#pragma unroll
        for (int j = 0; j < 4; j++) dl[i][j] = fmaf(ka[i], va[j], dl[i][j]);
    }
    __syncthreads();
  }

  float* dg = dots + ((size_t)(b * H_ + h)) * 4096;
#pragma unroll
  for (int i = 0; i < 4; i++)
#pragma unroll
    for (int j = 0; j < 4; j++)
      atomicAdd(&dg[(tr * 4 + i) * 64 + tc * 4 + j], dl[i][j]);
}

// ---------------------------------------------------------------------------
// Kernel 2a: S[b][hd][o] = sum_e dots[b,h,d,e] * Wo[o, h*64+e]
// ---------------------------------------------------------------------------
__global__ __launch_bounds__(256) void s_kernel(
    const float* __restrict__ dots, const float* __restrict__ Wo,
    float* __restrict__ S)
{
  const int blk = blockIdx.x;  // b*512 + hd
  const int b = blk >> 9, hd = blk & 511, h = hd >> 6;
  __shared__ float drow[64];
  const int t = threadIdx.x;
  if (t < 64) drow[t] = dots[((size_t)(b * H_ + h)) * 4096 + (hd & 63) * 64 + t];
  __syncthreads();
  const float* wp = Wo + (size_t)t * INNER_ + h * 64;
  float acc = 0.f;
#pragma unroll
  for (int e = 0; e < 64; e += 4) {
    const float4 w = *(const float4*)(wp + e);
    acc = fmaf(drow[e + 0], w.x, acc);
    acc = fmaf(drow[e + 1], w.y, acc);
    acc = fmaf(drow[e + 2], w.z, acc);
    acc = fmaf(drow[e + 3], w.w, acc);
  }
  S[((size_t)(b * INNER_) + hd) * COUT_ + t] = acc;
}

// ---------------------------------------------------------------------------
// Kernel 2b: Mbt[o][c] = (1/N) sum_hd Wq[hd][c] * S[b][hd][o], written
// transposed AND pre-split to bf16 hi/lo for the MFMA out-GEMM.
// ---------------------------------------------------------------------------
__global__ __launch_bounds__(256) void mb_kernel(
    const float* __restrict__ Wq, const float* __restrict__ S,
    ushort_t* __restrict__ MbtH, ushort_t* __restrict__ MbtL)
{
  __shared__ __align__(16) float wql[INNER_][16];
  const int c0 = blockIdx.x * 16, b = blockIdx.y;
  const int t = threadIdx.x;
#pragma unroll
  for (int i = 0; i < 32; i++) {
    const int idx = i * 256 + t;  // 0..8191
    wql[idx >> 4][idx & 15] = Wq[(size_t)(idx >> 4) * CIN_ + c0 + (idx & 15)];
  }
  __syncthreads();
  float acc[16];
#pragma unroll
  for (int cp = 0; cp < 16; cp++) acc[cp] = 0.f;
  const float* sp = S + (size_t)b * INNER_ * COUT_ + t;
  for (int hd = 0; hd < INNER_; hd++) {
    const float sv = sp[(size_t)hd * COUT_];
#pragma unroll
    for (int g = 0; g < 4; g++) {
      const float4 w = *(const float4*)&wql[hd][g * 4];
      acc[g * 4 + 0] = fmaf(w.x, sv, acc[g * 4 + 0]);
      acc[g * 4 + 1] = fmaf(w.y, sv, acc[g * 4 + 1]);
      acc[g * 4 + 2] = fmaf(w.z, sv, acc[g * 4 + 2]);
      acc[g * 4 + 3] = fmaf(w.w, sv, acc[g * 4 + 3]);
    }
  }
#pragma unroll
  for (int cp = 0; cp < 16; cp++) {
    const float v = acc[cp] * (1.0f / N_);
    ushort_t hi, lo;
    split_bf16(v, hi, lo);
    const size_t off = ((size_t)(b * COUT_) + t) * CIN_ + c0 + cp;
    MbtH[off] = hi;
    MbtL[off] = lo;
  }
}

// ---------------------------------------------------------------------------
// Kernel 3: out[b,n,o] = sum_c u_x[b,n,c] * Mbt[o][c] + bo[o], split-bf16 MFMA,
// 128x128 tile, 4 waves of 64x64. B staging is a pure ushort copy.
// ---------------------------------------------------------------------------
__global__ __launch_bounds__(256, 2) void out_kernel(
    const float* __restrict__ u_x, const ushort_t* __restrict__ MbtH,
    const ushort_t* __restrict__ MbtL, const float* __restrict__ bo,
    float* __restrict__ out)
{
  __shared__ __align__(16) char smem[33280];
  ushort_t (*Ah)[130][8] = (ushort_t(*)[130][8])(smem);
  ushort_t (*Al)[130][8] = (ushort_t(*)[130][8])(smem + 8320);
  ushort_t (*Bh)[130][8] = (ushort_t(*)[130][8])(smem + 16640);
  ushort_t (*Bl)[130][8] = (ushort_t(*)[130][8])(smem + 24960);

  const int t = threadIdx.x;
  const int r0 = blockIdx.x * 128, o0 = blockIdx.y * 128, b = blockIdx.z;
  const int lane = t & 63, wave = t >> 6;
  const int q = lane >> 4, r = lane & 15;
  const int m0 = (wave >> 1) * 64, n0 = (wave & 1) * 64;
  const int srow = t >> 1, scs = (t & 1) * 16, q0 = (t & 1) * 2;

  const float* ag = u_x + ((size_t)(b * N_) + r0 + srow) * CIN_ + scs;
  const ushort_t* bgh = MbtH + ((size_t)(b * COUT_) + o0 + srow) * CIN_ + scs;
  const ushort_t* bgl = MbtL + ((size_t)(b * COUT_) + o0 + srow) * CIN_ + scs;

  f32x4 acc[4][4];
#pragma unroll
  for (int i = 0; i < 4; i++)
#pragma unroll
    for (int j = 0; j < 4; j++) acc[i][j] = (f32x4)0.f;

  for (int kc = 0; kc < 8; kc++) {
    {
      const float4* ap = (const float4*)(ag + kc * 32);
      uint4 uh, ul;
      cvt8(ap[0], ap[1], uh, ul);
      *(uint4*)&Ah[q0][srow][0] = uh;  *(uint4*)&Al[q0][srow][0] = ul;
      cvt8(ap[2], ap[3], uh, ul);
      *(uint4*)&Ah[q0 + 1][srow][0] = uh;  *(uint4*)&Al[q0 + 1][srow][0] = ul;
      const uint4* bph = (const uint4*)(bgh + kc * 32);
      const uint4* bpl = (const uint4*)(bgl + kc * 32);
      *(uint4*)&Bh[q0][srow][0] = bph[0];  *(uint4*)&Bh[q0 + 1][srow][0] = bph[1];
      *(uint4*)&Bl[q0][srow][0] = bpl[0];  *(uint4*)&Bl[q0 + 1][srow][0] = bpl[1];
    }
    __syncthreads();
    short8 ahf[4], alf[4];
#pragma unroll
    for (int mi = 0; mi < 4; mi++) {
      ahf[mi] = *(const short8*)&Ah[q][m0 + 16 * mi + r][0];
      alf[mi] = *(const short8*)&Al[q][m0 + 16 * mi + r][0];
    }
#pragma unroll
    for (int nj = 0; nj < 4; nj++) {
      const short8 bhv = *(const short8*)&Bh[q][n0 + 16 * nj + r][0];
      const short8 blv = *(const short8*)&Bl[q][n0 + 16 * nj + r][0];
#pragma unroll
      for (int mi = 0; mi < 4; mi++) {
        acc[mi][nj] = MFMA(ahf[mi], bhv, acc[mi][nj]);
        acc[mi][nj] = MFMA(alf[mi], bhv, acc[mi][nj]);
        acc[mi][nj] = MFMA(ahf[mi], blv, acc[mi][nj]);
      }
    }
    __syncthreads();
  }

  float bov[4];
#pragma unroll
  for (int nj = 0; nj < 4; nj++) bov[nj] = bo[o0 + n0 + 16 * nj + r];
#pragma unroll
  for (int mi = 0; mi < 4; mi++)
#pragma unroll
    for (int nj = 0; nj < 4; nj++) {
      const f32x4 v = acc[mi][nj];
#pragma unroll
      for (int reg = 0; reg < 4; reg++) {
        const int row = r0 + m0 + 16 * mi + q * 4 + reg;
        out[((size_t)(b * N_) + row) * COUT_ + o0 + n0 + 16 * nj + r] =
            v[reg] + bov[nj];
      }
    }
}

extern "C" void kernel_launch(void* const* d_in, const int* in_sizes, int n_in,
                              void* d_out, int out_size, void* d_ws, size_t ws_size,
                              hipStream_t stream) {
  const float* u_x = (const float*)d_in[0];
  // d_in[1] = pos_x (unused)
  const float* Wq = (const float*)d_in[2];
  const float* Wk = (const float*)d_in[3];
  const float* Wv = (const float*)d_in[4];
  const float* Wo = (const float*)d_in[5];
  const float* bo = (const float*)d_in[6];
  float* out = (float*)d_out;

  float* dots    = (float*)d_ws;            // 131072 floats
  float* S       = dots + 131072;           // 524288 floats
  ushort_t* MbtH = (ushort_t*)(S + 524288); // 262144 ushorts
  ushort_t* MbtL = MbtH + 262144;           // 262144 ushorts

  hipMemsetAsync(dots, 0, 131072 * sizeof(float), stream);
  kv_dots_kernel<<<dim3(64, 8, 4), 256, 0, stream>>>(u_x, Wk, Wv, dots);
  s_kernel<<<2048, 256, 0, stream>>>(dots, Wo, S);
  mb_kernel<<<dim3(16, 4), 256, 0, stream>>>(Wq, S, MbtH, MbtL);
  out_kernel<<<dim3(64, 2, 4), 256, 0, stream>>>(u_x, MbtH, MbtL, bo, out);
}

// Round 4
// 230.142 us; speedup vs baseline: 2.2656x; 1.3760x over previous
//
#include <hip/hip_runtime.h>

// B=4, N=8192, CIN=256, H=8, D=64, INNER=512, COUT=256. fp32 I/O.
// out[b] = u_x[b] @ Mb[b] + bo via collapsed per-batch 256x256 matrix.
// All GEMMs: split-bf16 MFMA (x = hi + lo, 3 mfma terms, rel err ~2^-16).
// Inputs pre-split to bf16 hi/lo ONCE (prep kernels) so staging is pure copy.
// dots = Kn^T Vn also on MFMA via in-register InstanceNorm + LDS transpose.

#define B_    4
#define N_    8192
#define CIN_  256
#define H_    8
#define D_    64
#define INNER_ 512
#define COUT_ 256
#define EPS_  1e-5f

typedef unsigned short ushort_t;
typedef unsigned int   uint_t;
typedef __attribute__((ext_vector_type(8))) short short8;
typedef __attribute__((ext_vector_type(4))) float f32x4;

__device__ __forceinline__ void split_bf16(float x, ushort_t& hi, ushort_t& lo) {
  const uint_t u = __float_as_uint(x);
  const uint_t hr = (u + 0x8000u) & 0xffff0000u;   // round-half-up to bf16
  hi = (ushort_t)(hr >> 16);
  const float l = x - __uint_as_float(hr);          // exact residual
  lo = (ushort_t)((__float_as_uint(l) + 0x8000u) >> 16);
}

__device__ __forceinline__ void cvt8(float4 x, float4 y, uint4& uh, uint4& ul) {
  const float v[8] = {x.x, x.y, x.z, x.w, y.x, y.y, y.z, y.w};
  ushort_t h[8], l[8];
#pragma unroll
  for (int j = 0; j < 8; j++) split_bf16(v[j], h[j], l[j]);
  uh = make_uint4(h[0] | ((uint_t)h[1] << 16), h[2] | ((uint_t)h[3] << 16),
                  h[4] | ((uint_t)h[5] << 16), h[6] | ((uint_t)h[7] << 16));
  ul = make_uint4(l[0] | ((uint_t)l[1] << 16), l[2] | ((uint_t)l[3] << 16),
                  l[4] | ((uint_t)l[5] << 16), l[6] | ((uint_t)l[7] << 16));
}

#define MFMA(A, Bv, C) __builtin_amdgcn_mfma_f32_16x16x32_bf16((A), (Bv), (C), 0, 0, 0)

// ---------------------------------------------------------------------------
// Prep: split fp32 -> packed bf16 hi/lo global arrays.
// ---------------------------------------------------------------------------
__global__ __launch_bounds__(256) void prep_ux_kernel(
    const float* __restrict__ u_x, ushort_t* __restrict__ uxH,
    ushort_t* __restrict__ uxL)
{
  const size_t base = ((size_t)blockIdx.x * 256 + threadIdx.x) * 8;
  const float4 x = *(const float4*)(u_x + base);
  const float4 y = *(const float4*)(u_x + base + 4);
  uint4 uh, ul;
  cvt8(x, y, uh, ul);
  *(uint4*)(uxH + base) = uh;
  *(uint4*)(uxL + base) = ul;
}

__global__ __launch_bounds__(256) void prep_w_kernel(
    const float* __restrict__ Wk, const float* __restrict__ Wv,
    ushort_t* __restrict__ WkvH, ushort_t* __restrict__ WkvL)
{
  const size_t base = ((size_t)blockIdx.x * 256 + threadIdx.x) * 8;  // 0..262143
  const float* src = (base < 131072) ? (Wk + base) : (Wv + base - 131072);
  const float4 x = *(const float4*)(src);
  const float4 y = *(const float4*)(src + 4);
  uint4 uh, ul;
  cvt8(x, y, uh, ul);
  *(uint4*)(WkvH + base) = uh;
  *(uint4*)(WkvL + base) = ul;
}

// ---------------------------------------------------------------------------
// Kernel 1: per (chunk of 256 rows, h, b): 2 macro-tiles of 128 rows:
//   KV = u_x @ [Wk_h;Wv_h]^T (split-bf16 MFMA, pure-copy staging)
//   InstanceNorm in-register (per-wave cols are exactly one K/V half)
//   transpose normalized bf16 hi/lo -> LDS, dots += Kt.Vt^T on MFMA
// atomicAdd 64x64 dots per (b,h) at end.
// LDS: union(staging 33280 B, Kt/Vt 4x9216 B) = 36864 B.
// ---------------------------------------------------------------------------
__global__ __launch_bounds__(256, 2) void kv_dots_kernel(
    const ushort_t* __restrict__ uxH, const ushort_t* __restrict__ uxL,
    const ushort_t* __restrict__ WkvH, const ushort_t* __restrict__ WkvL,
    float* __restrict__ dots)
{
  __shared__ __align__(16) char smem[36864];
  ushort_t (*Ah)[130][8] = (ushort_t(*)[130][8])(smem);
  ushort_t (*Al)[130][8] = (ushort_t(*)[130][8])(smem + 8320);
  ushort_t (*Bh)[130][8] = (ushort_t(*)[130][8])(smem + 16640);
  ushort_t (*Bl)[130][8] = (ushort_t(*)[130][8])(smem + 24960);
  ushort_t* KtH = (ushort_t*)(smem);            // [64][72]
  ushort_t* KtL = (ushort_t*)(smem + 9216);
  ushort_t* VtH = (ushort_t*)(smem + 18432);
  ushort_t* VtL = (ushort_t*)(smem + 27648);

  const int t = threadIdx.x;
  const int chunk = blockIdx.x, h = blockIdx.y, b = blockIdx.z;
  const int lane = t & 63, wave = t >> 6;
  const int q = lane >> 4, r = lane & 15;
  const int m0 = (wave >> 1) * 64, n0 = (wave & 1) * 64;
  const int srow = t >> 1, scs = (t & 1) * 16, q0 = (t & 1) * 2;
  const int dstripe = 16 * wave;

  // weight row for this thread's B staging (fixed across macro-tiles)
  const int wr = (srow < 64) ? (h * 64 + srow) : (512 + h * 64 + srow - 64);
  const ushort_t* bgH = WkvH + (size_t)wr * CIN_ + scs;
  const ushort_t* bgL = WkvL + (size_t)wr * CIN_ + scs;

  f32x4 dacc[4];
#pragma unroll
  for (int j = 0; j < 4; j++) dacc[j] = (f32x4)0.f;

  for (int mt = 0; mt < 2; mt++) {
    const int r0 = chunk * 256 + mt * 128;
    const ushort_t* agH = uxH + ((size_t)(b * N_) + r0 + srow) * CIN_ + scs;
    const ushort_t* agL = uxL + ((size_t)(b * N_) + r0 + srow) * CIN_ + scs;

    f32x4 acc[4][4];
#pragma unroll
    for (int i = 0; i < 4; i++)
#pragma unroll
      for (int j = 0; j < 4; j++) acc[i][j] = (f32x4)0.f;

    for (int kc = 0; kc < 8; kc++) {
      // stage 32 k-cols (pure copies)
      *(uint4*)&Ah[q0][srow][0]     = *(const uint4*)(agH + kc * 32);
      *(uint4*)&Ah[q0 + 1][srow][0] = *(const uint4*)(agH + kc * 32 + 8);
      *(uint4*)&Al[q0][srow][0]     = *(const uint4*)(agL + kc * 32);
      *(uint4*)&Al[q0 + 1][srow][0] = *(const uint4*)(agL + kc * 32 + 8);
      *(uint4*)&Bh[q0][srow][0]     = *(const uint4*)(bgH + kc * 32);
      *(uint4*)&Bh[q0 + 1][srow][0] = *(const uint4*)(bgH + kc * 32 + 8);
      *(uint4*)&Bl[q0][srow][0]     = *(const uint4*)(bgL + kc * 32);
      *(uint4*)&Bl[q0 + 1][srow][0] = *(const uint4*)(bgL + kc * 32 + 8);
      __syncthreads();
      short8 ahf[4], alf[4];
#pragma unroll
      for (int mi = 0; mi < 4; mi++) {
        ahf[mi] = *(const short8*)&Ah[q][m0 + 16 * mi + r][0];
        alf[mi] = *(const short8*)&Al[q][m0 + 16 * mi + r][0];
      }
#pragma unroll
      for (int nj = 0; nj < 4; nj++) {
        const short8 bhv = *(const short8*)&Bh[q][n0 + 16 * nj + r][0];
        const short8 blv = *(const short8*)&Bl[q][n0 + 16 * nj + r][0];
#pragma unroll
        for (int mi = 0; mi < 4; mi++) {
          acc[mi][nj] = MFMA(ahf[mi], bhv, acc[mi][nj]);
          acc[mi][nj] = MFMA(alf[mi], bhv, acc[mi][nj]);
          acc[mi][nj] = MFMA(ahf[mi], blv, acc[mi][nj]);
        }
      }
      __syncthreads();
    }

    // ---- InstanceNorm in-register. Wave's 64 cols are one K/V half; row
    // (seq index) = m0 + 16mi + 4q + reg; stats over 64 cols = sum over nj
    // then over the 16 lanes of the quad.
    float mean[4][4], inv[4][4];
#pragma unroll
    for (int mi = 0; mi < 4; mi++)
#pragma unroll
      for (int reg = 0; reg < 4; reg++) {
        float rs = 0.f, rq = 0.f;
#pragma unroll
        for (int nj = 0; nj < 4; nj++) {
          const float v = acc[mi][nj][reg];
          rs += v;
          rq = fmaf(v, v, rq);
        }
#pragma unroll
        for (int msk = 1; msk < 16; msk <<= 1) {
          rs += __shfl_xor(rs, msk, 64);
          rq += __shfl_xor(rq, msk, 64);
        }
        const float m = rs * (1.f / 64.f);
        const float var = fmaxf(rq * (1.f / 64.f) - m * m, 0.f);
        mean[mi][reg] = m;
        inv[mi][reg] = rsqrtf(var + EPS_);
      }
#pragma unroll
    for (int mi = 0; mi < 4; mi++)
#pragma unroll
      for (int nj = 0; nj < 4; nj++)
#pragma unroll
        for (int reg = 0; reg < 4; reg++)
          acc[mi][nj][reg] = (acc[mi][nj][reg] - mean[mi][reg]) * inv[mi][reg];

    // ---- two 64-row halves: transpose to LDS (bf16 hi/lo), dots MFMA
    for (int p = 0; p < 2; p++) {
      if ((wave >> 1) == p) {
        ushort_t* Hd = (wave & 1) ? VtH : KtH;
        ushort_t* Ld = (wave & 1) ? VtL : KtL;
#pragma unroll
        for (int nj = 0; nj < 4; nj++) {
          const int d = 16 * nj + r;
#pragma unroll
          for (int mi = 0; mi < 4; mi++) {
            const int nb = 16 * mi + 4 * q;
            ushort_t hh[4], ll[4];
#pragma unroll
            for (int reg = 0; reg < 4; reg++)
              split_bf16(acc[mi][nj][reg], hh[reg], ll[reg]);
            uint2 ph, pl;
            ph.x = hh[0] | ((uint_t)hh[1] << 16);
            ph.y = hh[2] | ((uint_t)hh[3] << 16);
            pl.x = ll[0] | ((uint_t)ll[1] << 16);
            pl.y = ll[2] | ((uint_t)ll[3] << 16);
            *(uint2*)&Hd[d * 72 + nb] = ph;
            *(uint2*)&Ld[d * 72 + nb] = pl;
          }
        }
      }
      __syncthreads();
#pragma unroll
      for (int ks = 0; ks < 2; ks++) {
        const short8 aH = *(const short8*)&KtH[(dstripe + r) * 72 + ks * 32 + q * 8];
        const short8 aL = *(const short8*)&KtL[(dstripe + r) * 72 + ks * 32 + q * 8];
#pragma unroll
        for (int ej = 0; ej < 4; ej++) {
          const short8 bH = *(const short8*)&VtH[(16 * ej + r) * 72 + ks * 32 + q * 8];
          const short8 bL = *(const short8*)&VtL[(16 * ej + r) * 72 + ks * 32 + q * 8];
          dacc[ej] = MFMA(aH, bH, dacc[ej]);
          dacc[ej] = MFMA(aL, bH, dacc[ej]);
          dacc[ej] = MFMA(aH, bL, dacc[ej]);
        }
      }
      __syncthreads();
    }
  }

  float* dg = dots + ((size_t)(b * H_ + h)) * 4096;
#pragma unroll
  for (int ej = 0; ej < 4; ej++)
#pragma unroll
    for (int reg = 0; reg < 4; reg++)
      atomicAdd(&dg[(dstripe + 4 * q + reg) * 64 + 16 * ej + r], dacc[ej][reg]);
}

// ---------------------------------------------------------------------------
// Kernel 2a: S[b][hd][o] = sum_e dots[b,h,d,e] * Wo[o, h*64+e]
// ---------------------------------------------------------------------------
__global__ __launch_bounds__(256) void s_kernel(
    const float* __restrict__ dots, const float* __restrict__ Wo,
    float* __restrict__ S)
{
  const int blk = blockIdx.x;  // b*512 + hd
  const int b = blk >> 9, hd = blk & 511, h = hd >> 6;
  __shared__ float drow[64];
  const int t = threadIdx.x;
  if (t < 64) drow[t] = dots[((size_t)(b * H_ + h)) * 4096 + (hd & 63) * 64 + t];
  __syncthreads();
  const float* wp = Wo + (size_t)t * INNER_ + h * 64;
  float acc = 0.f;
#pragma unroll
  for (int e = 0; e < 64; e += 4) {
    const float4 w = *(const float4*)(wp + e);
    acc = fmaf(drow[e + 0], w.x, acc);
    acc = fmaf(drow[e + 1], w.y, acc);
    acc = fmaf(drow[e + 2], w.z, acc);
    acc = fmaf(drow[e + 3], w.w, acc);
  }
  S[((size_t)(b * INNER_) + hd) * COUT_ + t] = acc;
}

// ---------------------------------------------------------------------------
// Kernel 2b: partial Mb over hd-chunks of 128 (grid: 16 c-tiles x 4 b x 4 s)
// ---------------------------------------------------------------------------
__global__ __launch_bounds__(256) void mb_part_kernel(
    const float* __restrict__ Wq, const float* __restrict__ S,
    float* __restrict__ Mbp)
{
  __shared__ __align__(16) float wql[128][16];
  const int c0 = blockIdx.x * 16, b = blockIdx.y, s = blockIdx.z;
  const int t = threadIdx.x;
#pragma unroll
  for (int i = 0; i < 8; i++) {
    const int idx = i * 256 + t;  // 0..2047
    wql[idx >> 4][idx & 15] = Wq[(size_t)(s * 128 + (idx >> 4)) * CIN_ + c0 + (idx & 15)];
  }
  __syncthreads();
  float acc[16];
#pragma unroll
  for (int cp = 0; cp < 16; cp++) acc[cp] = 0.f;
  const float* sp = S + ((size_t)(b * INNER_) + s * 128) * COUT_ + t;
  for (int hd = 0; hd < 128; hd++) {
    const float sv = sp[(size_t)hd * COUT_];
#pragma unroll
    for (int g = 0; g < 4; g++) {
      const float4 w = *(const float4*)&wql[hd][g * 4];
      acc[g * 4 + 0] = fmaf(w.x, sv, acc[g * 4 + 0]);
      acc[g * 4 + 1] = fmaf(w.y, sv, acc[g * 4 + 1]);
      acc[g * 4 + 2] = fmaf(w.z, sv, acc[g * 4 + 2]);
      acc[g * 4 + 3] = fmaf(w.w, sv, acc[g * 4 + 3]);
    }
  }
#pragma unroll
  for (int cp = 0; cp < 16; cp++)
    Mbp[(((size_t)s * 4 + b) * CIN_ + c0 + cp) * COUT_ + t] = acc[cp];
}

// ---------------------------------------------------------------------------
// Kernel 2c: merge 4 partials, scale 1/N, split bf16, write transposed Mbt.
// ---------------------------------------------------------------------------
__global__ __launch_bounds__(256) void mb_merge_kernel(
    const float* __restrict__ Mbp, ushort_t* __restrict__ MbtH,
    ushort_t* __restrict__ MbtL)
{
  const int c0 = blockIdx.x * 16, b = blockIdx.y;
  const int o = threadIdx.x;
#pragma unroll
  for (int cp = 0; cp < 16; cp++) {
    const int c = c0 + cp;
    float v = 0.f;
#pragma unroll
    for (int s = 0; s < 4; s++)
      v += Mbp[(((size_t)s * 4 + b) * CIN_ + c) * COUT_ + o];
    v *= (1.0f / N_);
    ushort_t hi, lo;
    split_bf16(v, hi, lo);
    const size_t off = ((size_t)(b * COUT_) + o) * CIN_ + c;
    MbtH[off] = hi;
    MbtL[off] = lo;
  }
}

// ---------------------------------------------------------------------------
// Kernel 3: out[b,n,o] = sum_c u_x[b,n,c] * Mbt[o][c] + bo[o], split-bf16
// MFMA, 128x128 tile; all staging is pure copies.
// ---------------------------------------------------------------------------
__global__ __launch_bounds__(256, 2) void out_kernel(
    const ushort_t* __restrict__ uxH, const ushort_t* __restrict__ uxL,
    const ushort_t* __restrict__ MbtH, const ushort_t* __restrict__ MbtL,
    const float* __restrict__ bo, float* __restrict__ out)
{
  __shared__ __align__(16) char smem[33280];
  ushort_t (*Ah)[130][8] = (ushort_t(*)[130][8])(smem);
  ushort_t (*Al)[130][8] = (ushort_t(*)[130][8])(smem + 8320);
  ushort_t (*Bh)[130][8] = (ushort_t(*)[130][8])(smem + 16640);
  ushort_t (*Bl)[130][8] = (ushort_t(*)[130][8])(smem + 24960);

  const int t = threadIdx.x;
  const int r0 = blockIdx.x * 128, o0 = blockIdx.y * 128, b = blockIdx.z;
  const int lane = t & 63, wave = t >> 6;
  const int q = lane >> 4, r = lane & 15;
  const int m0 = (wave >> 1) * 64, n0 = (wave & 1) * 64;
  const int srow = t >> 1, scs = (t & 1) * 16, q0 = (t & 1) * 2;

  const ushort_t* agH = uxH + ((size_t)(b * N_) + r0 + srow) * CIN_ + scs;
  const ushort_t* agL = uxL + ((size_t)(b * N_) + r0 + srow) * CIN_ + scs;
  const ushort_t* bgH = MbtH + ((size_t)(b * COUT_) + o0 + srow) * CIN_ + scs;
  const ushort_t* bgL = MbtL + ((size_t)(b * COUT_) + o0 + srow) * CIN_ + scs;

  f32x4 acc[4][4];
#pragma unroll
  for (int i = 0; i < 4; i++)
#pragma unroll
    for (int j = 0; j < 4; j++) acc[i][j] = (f32x4)0.f;

  for (int kc = 0; kc < 8; kc++) {
    *(uint4*)&Ah[q0][srow][0]     = *(const uint4*)(agH + kc * 32);
    *(uint4*)&Ah[q0 + 1][srow][0] = *(const uint4*)(agH + kc * 32 + 8);
    *(uint4*)&Al[q0][srow][0]     = *(const uint4*)(agL + kc * 32);
    *(uint4*)&Al[q0 + 1][srow][0] = *(const uint4*)(agL + kc * 32 + 8);
    *(uint4*)&Bh[q0][srow][0]     = *(const uint4*)(bgH + kc * 32);
    *(uint4*)&Bh[q0 + 1][srow][0] = *(const uint4*)(bgH + kc * 32 + 8);
    *(uint4*)&Bl[q0][srow][0]     = *(const uint4*)(bgL + kc * 32);
    *(uint4*)&Bl[q0 + 1][srow][0] = *(const uint4*)(bgL + kc * 32 + 8);
    __syncthreads();
    short8 ahf[4], alf[4];
#pragma unroll
    for (int mi = 0; mi < 4; mi++) {
      ahf[mi] = *(const short8*)&Ah[q][m0 + 16 * mi + r][0];
      alf[mi] = *(const short8*)&Al[q][m0 + 16 * mi + r][0];
    }
#pragma unroll
    for (int nj = 0; nj < 4; nj++) {
      const short8 bhv = *(const short8*)&Bh[q][n0 + 16 * nj + r][0];
      const short8 blv = *(const short8*)&Bl[q][n0 + 16 * nj + r][0];
#pragma unroll
      for (int mi = 0; mi < 4; mi++) {
        acc[mi][nj] = MFMA(ahf[mi], bhv, acc[mi][nj]);
        acc[mi][nj] = MFMA(alf[mi], bhv, acc[mi][nj]);
        acc[mi][nj] = MFMA(ahf[mi], blv, acc[mi][nj]);
      }
    }
    __syncthreads();
  }

  float bov[4];
#pragma unroll
  for (int nj = 0; nj < 4; nj++) bov[nj] = bo[o0 + n0 + 16 * nj + r];
#pragma unroll
  for (int mi = 0; mi < 4; mi++)
#pragma unroll
    for (int nj = 0; nj < 4; nj++) {
      const f32x4 v = acc[mi][nj];
#pragma unroll
      for (int reg = 0; reg < 4; reg++) {
        const int row = r0 + m0 + 16 * mi + q * 4 + reg;
        out[((size_t)(b * N_) + row) * COUT_ + o0 + n0 + 16 * nj + r] =
            v[reg] + bov[nj];
      }
    }
}

extern "C" void kernel_launch(void* const* d_in, const int* in_sizes, int n_in,
                              void* d_out, int out_size, void* d_ws, size_t ws_size,
                              hipStream_t stream) {
  const float* u_x = (const float*)d_in[0];
  // d_in[1] = pos_x (unused)
  const float* Wq = (const float*)d_in[2];
  const float* Wk = (const float*)d_in[3];
  const float* Wv = (const float*)d_in[4];
  const float* Wo = (const float*)d_in[5];
  const float* bo = (const float*)d_in[6];
  float* out = (float*)d_out;

  // ws layout
  ushort_t* uxH  = (ushort_t*)d_ws;        // 8388608
  ushort_t* uxL  = uxH + 8388608;          // 8388608
  ushort_t* WkvH = uxL + 8388608;          // 262144
  ushort_t* WkvL = WkvH + 262144;          // 262144
  ushort_t* MbtH = WkvL + 262144;          // 262144
  ushort_t* MbtL = MbtH + 262144;          // 262144
  float* dots = (float*)(MbtL + 262144);   // 131072 floats
  float* S    = dots + 131072;             // 524288 floats
  float* Mbp  = S + 524288;                // 1048576 floats

  prep_ux_kernel<<<4096, 256, 0, stream>>>(u_x, uxH, uxL);
  prep_w_kernel<<<128, 256, 0, stream>>>(Wk, Wv, WkvH, WkvL);
  hipMemsetAsync(dots, 0, 131072 * sizeof(float), stream);
  kv_dots_kernel<<<dim3(32, 8, 4), 256, 0, stream>>>(uxH, uxL, WkvH, WkvL, dots);
  s_kernel<<<2048, 256, 0, stream>>>(dots, Wo, S);
  mb_part_kernel<<<dim3(16, 4, 4), 256, 0, stream>>>(Wq, S, Mbp);
  mb_merge_kernel<<<dim3(16, 4), 256, 0, stream>>>(Mbp, MbtH, MbtL);
  out_kernel<<<dim3(64, 2, 4), 256, 0, stream>>>(uxH, uxL, MbtH, MbtL, bo, out);
}